// Round 1
// baseline (1450.028 us; speedup 1.0000x reference)
//
#include <hip/hip_runtime.h>

// Problem constants (static per reference)
#define B_SZ   16
#define N_NODES 1024
#define P_TOK  256
#define D_DIM  64
#define K_ANCH 26   // ceil(256 * 0.1)

// ---------------------------------------------------------------------------
// K1: importance[j] = mean over i of adp[i, j]   (column mean of [1024,1024])
// ---------------------------------------------------------------------------
__global__ void k_importance(const float* __restrict__ adp,
                             float* __restrict__ imp) {
    int j = blockIdx.x * blockDim.x + threadIdx.x;   // 0..1023
    float s = 0.f;
    #pragma unroll 8
    for (int i = 0; i < N_NODES; ++i)
        s += adp[i * N_NODES + j];                   // coalesced across j
    imp[j] = s * (1.0f / N_NODES);
}

// ---------------------------------------------------------------------------
// K2: fused pass over patches [b, n, p, d]:
//   scores[b,p]      = sum_n sqrt(sum_d patches^2) * importance[n]
//   mean_tokens[b,p,d] = mean_n patches
// One wave (64 threads) per (b,p). Lane layout: g = t>>4 handles n = n0+g,
// d4 = t&15 handles d-slice [4*d4, 4*d4+4) as float4.
// Per-iteration wave load = 4 contiguous 256B segments (fully coalesced).
// ---------------------------------------------------------------------------
__global__ __launch_bounds__(64)
void k_scores_means(const float* __restrict__ patches,
                    const float* __restrict__ imp,
                    float* __restrict__ scores,
                    float4* __restrict__ mean4) {
    __shared__ float s_imp[N_NODES];
    int t = threadIdx.x;
    for (int i = t; i < N_NODES; i += 64) s_imp[i] = imp[i];
    __syncthreads();

    int b  = blockIdx.x >> 8;     // / P_TOK
    int p  = blockIdx.x & 255;    // % P_TOK
    int g  = t >> 4;              // n-subgroup 0..3
    int d4 = t & 15;              // float4 slot in d

    const float4* base = (const float4*)patches;
    // float4 index of (b, n, p, d4) = ((b*N + n)*P + p)*16 + d4
    unsigned row0 = ((unsigned)b * N_NODES) * P_TOK + (unsigned)p;

    float4 macc = make_float4(0.f, 0.f, 0.f, 0.f);
    float score = 0.f;

    #pragma unroll 4
    for (int n0 = 0; n0 < N_NODES; n0 += 4) {
        int n = n0 + g;
        float4 v = base[(size_t)(row0 + (unsigned)n * P_TOK) * 16u + (unsigned)d4];
        macc.x += v.x; macc.y += v.y; macc.z += v.z; macc.w += v.w;
        float sq = v.x * v.x + v.y * v.y + v.z * v.z + v.w * v.w;
        // reduce sum-of-squares across the 16 lanes of this n-row
        sq += __shfl_xor(sq, 1);
        sq += __shfl_xor(sq, 2);
        sq += __shfl_xor(sq, 4);
        sq += __shfl_xor(sq, 8);
        score += sqrtf(sq) * s_imp[n];
    }

    // combine the 4 n-subgroups (each group's value replicated over 16 lanes)
    score += __shfl_xor(score, 16);
    score += __shfl_xor(score, 32);
    macc.x += __shfl_xor(macc.x, 16);  macc.x += __shfl_xor(macc.x, 32);
    macc.y += __shfl_xor(macc.y, 16);  macc.y += __shfl_xor(macc.y, 32);
    macc.z += __shfl_xor(macc.z, 16);  macc.z += __shfl_xor(macc.z, 32);
    macc.w += __shfl_xor(macc.w, 16);  macc.w += __shfl_xor(macc.w, 32);

    if (t < 16) {
        const float inv = 1.0f / N_NODES;
        float4 m = make_float4(macc.x * inv, macc.y * inv, macc.z * inv, macc.w * inv);
        mean4[(size_t)(b * P_TOK + p) * 16 + d4] = m;
    }
    if (t == 0)
        scores[b * P_TOK + p] = score;
}

// ---------------------------------------------------------------------------
// K3: top-k=26 per batch by rank counting. Exact jax.lax.top_k semantics:
// descending by value, ties broken by lower index.
// ---------------------------------------------------------------------------
__global__ __launch_bounds__(P_TOK)
void k_topk(const float* __restrict__ scores, int* __restrict__ topk) {
    __shared__ float s[P_TOK];
    int b = blockIdx.x;
    int j = threadIdx.x;
    float v = scores[b * P_TOK + j];
    s[j] = v;
    __syncthreads();
    int rank = 0;
    #pragma unroll 8
    for (int i = 0; i < P_TOK; ++i) {
        float si = s[i];
        rank += (si > v) || (si == v && i < j);
    }
    if (rank < K_ANCH)
        topk[b * K_ANCH + rank] = j;
}

// ---------------------------------------------------------------------------
// K4: gather compact anchors [b, k, d] from mean_tokens via topk indices
// ---------------------------------------------------------------------------
__global__ __launch_bounds__(64)
void k_gather(const float* __restrict__ mean_t,
              const int* __restrict__ topk,
              float* __restrict__ anchors) {
    int pair = blockIdx.x;            // b*K + kk, 0..415
    int b = pair / K_ANCH;
    int idx = topk[pair];
    anchors[pair * D_DIM + threadIdx.x] =
        mean_t[((size_t)(b * P_TOK + idx)) * D_DIM + threadIdx.x];
}

// ---------------------------------------------------------------------------
// K5: broadcast anchors [b, k*d] to out [b, n, k*d].  Pure streaming write.
// ---------------------------------------------------------------------------
__global__ void k_broadcast(const float4* __restrict__ anchors4,
                            float4* __restrict__ out4,
                            unsigned total4) {
    const unsigned PER_B = (unsigned)N_NODES * K_ANCH * D_DIM / 4;  // 425984
    const unsigned ROW4  = (unsigned)K_ANCH * D_DIM / 4;            // 416
    unsigned stride = gridDim.x * blockDim.x;
    for (unsigned f = blockIdx.x * blockDim.x + threadIdx.x; f < total4; f += stride) {
        unsigned b = f / PER_B;       // magic-mul division
        unsigned r = f % ROW4;        // 425984 % 416 == 0, so this is exact
        out4[f] = anchors4[b * ROW4 + r];
    }
}

// ---------------------------------------------------------------------------
extern "C" void kernel_launch(void* const* d_in, const int* in_sizes, int n_in,
                              void* d_out, int out_size, void* d_ws, size_t ws_size,
                              hipStream_t stream) {
    const float* patches = (const float*)d_in[0];   // [16,1024,256,64] fp32
    const float* adp     = (const float*)d_in[1];   // [1024,1024] fp32
    float* out = (float*)d_out;                     // [16*1024, 26, 64] fp32

    // ws layout (bytes): imp 4096 | scores 16384 | topk 1664 | pad | anchors 106496
    char* ws = (char*)d_ws;
    float* imp     = (float*)(ws + 0);
    float* scores  = (float*)(ws + 4096);
    int*   topk    = (int*)  (ws + 4096 + 16384);
    float* anchors = (float*)(ws + 4096 + 16384 + 2048);   // 16B-aligned

    // mean_tokens [16,256,64] fp32 = 1 MB staged in d_out (fully overwritten by K5)
    float* mean_t = out;

    k_importance<<<dim3(N_NODES / 256), dim3(256), 0, stream>>>(adp, imp);

    k_scores_means<<<dim3(B_SZ * P_TOK), dim3(64), 0, stream>>>(
        patches, imp, scores, (float4*)mean_t);

    k_topk<<<dim3(B_SZ), dim3(P_TOK), 0, stream>>>(scores, topk);

    k_gather<<<dim3(B_SZ * K_ANCH), dim3(64), 0, stream>>>(mean_t, topk, anchors);

    unsigned total4 = (unsigned)out_size / 4;       // 6,815,744 float4
    k_broadcast<<<dim3(4096), dim3(256), 0, stream>>>(
        (const float4*)anchors, (float4*)out, total4);
}

// Round 2
// 1379.900 us; speedup vs baseline: 1.0508x; 1.0508x over previous
//
#include <hip/hip_runtime.h>

// Problem constants (static per reference)
#define B_SZ    16
#define N_NODES 1024
#define P_TOK   256
#define D_DIM   64
#define K_ANCH  26   // ceil(256 * 0.1)

// ---------------------------------------------------------------------------
// K1a: partial column sums of adp [1024,1024].
// grid (4 col-chunks, 16 row-chunks), block 256.
// partial[rc*1024 + j] = sum over 64 rows of adp[., j]
// ---------------------------------------------------------------------------
__global__ __launch_bounds__(256)
void k_imp_partial(const float* __restrict__ adp, float* __restrict__ partial) {
    int j  = blockIdx.x * 256 + threadIdx.x;   // column
    int rc = blockIdx.y;                       // row chunk 0..15
    const float* src = adp + (size_t)rc * 64 * N_NODES + j;
    float s = 0.f;
    #pragma unroll 8
    for (int i = 0; i < 64; ++i)
        s += src[i * N_NODES];                 // coalesced across j
    partial[rc * N_NODES + j] = s;
}

// K1b: importance[j] = (1/1024) * sum over 16 partials
__global__ __launch_bounds__(256)
void k_imp_final(const float* __restrict__ partial, float* __restrict__ imp) {
    int j = blockIdx.x * 256 + threadIdx.x;
    float s = 0.f;
    #pragma unroll
    for (int rc = 0; rc < 16; ++rc)
        s += partial[rc * N_NODES + j];
    imp[j] = s * (1.0f / N_NODES);
}

// ---------------------------------------------------------------------------
// K2: fused pass over patches [b, n, p, d]:
//   scores[b,p]        = sum_n sqrt(sum_d patches^2) * importance[n]
//   mean_tokens[b,p,d] = mean_n patches
// Block = 256 threads (4 waves) per (b,p); wave w covers n in [256w, 256w+256).
// Within a wave: g = lane>>4 handles n = nbase+n0+g, d4 = lane&15 is the
// float4 slot in d. Per load instr a 16-lane group reads one contiguous 256B
// segment (exact-fetch, no L1 capacity pressure). 32 waves/CU, unroll 8
// -> ~8KB in flight per wave, far above BW*latency per CU.
// ---------------------------------------------------------------------------
__global__ __launch_bounds__(256)
void k_scores_means(const float* __restrict__ patches,
                    const float* __restrict__ imp,
                    float* __restrict__ scores,
                    float4* __restrict__ mean4) {
    __shared__ float  s_imp[N_NODES];
    __shared__ float4 s_macc[4][16];
    __shared__ float  s_score[4];

    int t = threadIdx.x;
    for (int i = t; i < N_NODES; i += 256) s_imp[i] = imp[i];
    __syncthreads();

    int b    = blockIdx.x >> 8;    // / P_TOK
    int p    = blockIdx.x & 255;   // % P_TOK
    int w    = t >> 6;             // wave 0..3
    int lane = t & 63;
    int g    = lane >> 4;          // n-subgroup 0..3
    int d4   = lane & 15;          // float4 slot in d

    // float4 pointer at (b, n=0, p, d4); per-n float4 stride = P_TOK*16 = 4096
    const float4* base = (const float4*)patches
                       + ((size_t)b * N_NODES * P_TOK + p) * 16 + d4;

    float4 macc = make_float4(0.f, 0.f, 0.f, 0.f);
    float score = 0.f;
    int nbase = w * 256;

    #pragma unroll 8
    for (int n0 = 0; n0 < 256; n0 += 4) {
        int n = nbase + n0 + g;
        float4 v = base[(size_t)n * (P_TOK * 16)];
        macc.x += v.x; macc.y += v.y; macc.z += v.z; macc.w += v.w;
        float sq = v.x * v.x + v.y * v.y + v.z * v.z + v.w * v.w;
        // reduce sum-of-squares across the 16 lanes of this n-row
        sq += __shfl_xor(sq, 1);
        sq += __shfl_xor(sq, 2);
        sq += __shfl_xor(sq, 4);
        sq += __shfl_xor(sq, 8);
        score += sqrtf(sq) * s_imp[n];
    }

    // combine the 4 n-subgroups inside the wave
    score += __shfl_xor(score, 16);
    score += __shfl_xor(score, 32);
    macc.x += __shfl_xor(macc.x, 16);  macc.x += __shfl_xor(macc.x, 32);
    macc.y += __shfl_xor(macc.y, 16);  macc.y += __shfl_xor(macc.y, 32);
    macc.z += __shfl_xor(macc.z, 16);  macc.z += __shfl_xor(macc.z, 32);
    macc.w += __shfl_xor(macc.w, 16);  macc.w += __shfl_xor(macc.w, 32);

    if (lane < 16) s_macc[w][d4] = macc;
    if (lane == 0) s_score[w] = score;
    __syncthreads();

    if (t < 16) {
        float4 a = s_macc[0][t], b2 = s_macc[1][t], c = s_macc[2][t], d = s_macc[3][t];
        const float inv = 1.0f / N_NODES;
        float4 m = make_float4((a.x + b2.x + c.x + d.x) * inv,
                               (a.y + b2.y + c.y + d.y) * inv,
                               (a.z + b2.z + c.z + d.z) * inv,
                               (a.w + b2.w + c.w + d.w) * inv);
        mean4[(size_t)(b * P_TOK + p) * 16 + t] = m;
    }
    if (t == 0)
        scores[b * P_TOK + p] = s_score[0] + s_score[1] + s_score[2] + s_score[3];
}

// ---------------------------------------------------------------------------
// K3: fused top-k (rank counting, exact jax.lax.top_k tie semantics:
// value desc, lower index first) + gather of compact anchors [b, k, d].
// One 256-thread block per batch.
// ---------------------------------------------------------------------------
__global__ __launch_bounds__(P_TOK)
void k_topk_gather(const float* __restrict__ scores,
                   const float4* __restrict__ mean4,
                   float4* __restrict__ anchors4) {
    __shared__ float s[P_TOK];
    int b = blockIdx.x;
    int j = threadIdx.x;
    float v = scores[b * P_TOK + j];
    s[j] = v;
    __syncthreads();
    int rank = 0;
    #pragma unroll 8
    for (int i = 0; i < P_TOK; ++i) {
        float si = s[i];
        rank += (si > v) || (si == v && i < j);
    }
    if (rank < K_ANCH) {
        const float4* src = mean4   + (size_t)(b * P_TOK + j)     * 16;
        float4*       dst = anchors4 + (size_t)(b * K_ANCH + rank) * 16;
        #pragma unroll
        for (int i = 0; i < 16; ++i) dst[i] = src[i];
    }
}

// ---------------------------------------------------------------------------
// K4: broadcast anchors [b, k*d] to out [b, n, k*d].  Pure streaming write;
// anchors (106 KB) stays L1/L2-resident.
// ---------------------------------------------------------------------------
__global__ __launch_bounds__(256)
void k_broadcast(const float4* __restrict__ anchors4,
                 float4* __restrict__ out4,
                 unsigned total4) {
    const unsigned PER_B = (unsigned)N_NODES * K_ANCH * D_DIM / 4;  // 425984
    const unsigned ROW4  = (unsigned)K_ANCH * D_DIM / 4;            // 416 (PER_B % ROW4 == 0)
    unsigned stride = gridDim.x * blockDim.x;
    for (unsigned f = blockIdx.x * blockDim.x + threadIdx.x; f < total4; f += stride) {
        unsigned b = f / PER_B;       // magic-mul division
        unsigned r = f % ROW4;        // exact because PER_B is a multiple of ROW4
        out4[f] = anchors4[b * ROW4 + r];
    }
}

// ---------------------------------------------------------------------------
extern "C" void kernel_launch(void* const* d_in, const int* in_sizes, int n_in,
                              void* d_out, int out_size, void* d_ws, size_t ws_size,
                              hipStream_t stream) {
    const float* patches = (const float*)d_in[0];   // [16,1024,256,64] fp32
    const float* adp     = (const float*)d_in[1];   // [1024,1024] fp32
    float* out = (float*)d_out;                     // [16*1024, 26, 64] fp32

    // ws layout (bytes, all 16B-aligned):
    //   imp     @ 0      (4096)
    //   scores  @ 4096   (16384)
    //   partial @ 20480  (65536)
    //   anchors @ 86016  (106496)
    char* ws = (char*)d_ws;
    float* imp     = (float*)(ws + 0);
    float* scores  = (float*)(ws + 4096);
    float* partial = (float*)(ws + 20480);
    float* anchors = (float*)(ws + 86016);

    // mean_tokens [16,256,64] fp32 = 1 MB staged in d_out (fully overwritten by K4)
    float4* mean4 = (float4*)out;

    k_imp_partial<<<dim3(N_NODES / 256, 16), dim3(256), 0, stream>>>(adp, partial);
    k_imp_final  <<<dim3(N_NODES / 256),     dim3(256), 0, stream>>>(partial, imp);

    k_scores_means<<<dim3(B_SZ * P_TOK), dim3(256), 0, stream>>>(
        patches, imp, scores, mean4);

    k_topk_gather<<<dim3(B_SZ), dim3(P_TOK), 0, stream>>>(
        scores, mean4, (float4*)anchors);

    unsigned total4 = (unsigned)out_size / 4;       // 6,815,744 float4
    k_broadcast<<<dim3(4096), dim3(256), 0, stream>>>(
        (const float4*)anchors, (float4*)out, total4);
}